// Round 1
// baseline (173.031 us; speedup 1.0000x reference)
//
#include <hip/hip_runtime.h>

#define N_TOTAL 16384
#define NODE_DIM 64
#define HIDDEN 128
#define NPG 2048
#define NGRAPH 8

// ---------------------------------------------------------------- K detect
// Distinguish int32 vs int64 edge_index on-device (no host sync allowed).
// int64 little-endian with values < 2^31 => every odd 32-bit word is 0.
__global__ void k_detect_idx(const int* __restrict__ ei, int* __restrict__ flag) {
    if (threadIdx.x == 0 && blockIdx.x == 0) {
        int odd_nonzero = 0;
        for (int i = 0; i < 256; ++i)
            if (ei[2 * i + 1] != 0) odd_nonzero = 1;
        *flag = odd_nonzero;   // 1 => int32 layout, 0 => int64 layout
    }
}

// ---------------------------------------------------------------- K1
// s[i] = rowsum(x[i,0:64]); zero agg1, deg. One wave per row.
__global__ __launch_bounds__(256) void k1_rowsum64(
    const float* __restrict__ x, float* __restrict__ s,
    float* __restrict__ agg1, float* __restrict__ deg) {
    int row  = blockIdx.x * 4 + (threadIdx.x >> 6);
    int lane = threadIdx.x & 63;
    float v = x[row * NODE_DIM + lane];
    for (int off = 32; off; off >>= 1) v += __shfl_xor(v, off);
    if (lane == 0) { s[row] = v; agg1[row] = 0.f; deg[row] = 0.f; }
}

// ---------------------------------------------------------------- K2/K5
// Edge scatter: agg[dst] += s[src]; optionally deg[dst] += 1.
__global__ __launch_bounds__(256) void k_edge(
    const void* __restrict__ ei_raw, int E, const int* __restrict__ flag,
    const float* __restrict__ s, float* __restrict__ agg,
    float* __restrict__ deg /* may be nullptr */) {
    int e = blockIdx.x * blockDim.x + threadIdx.x;
    if (e >= E) return;
    int sidx, didx;
    if (*flag) {
        const int* ei = (const int*)ei_raw;
        sidx = ei[e]; didx = ei[E + e];
    } else {
        const long long* ei = (const long long*)ei_raw;
        sidx = (int)ei[e]; didx = (int)ei[E + e];
    }
    atomicAdd(&agg[didx], s[sidx]);
    if (deg) atomicAdd(&deg[didx], 1.0f);
}

// ---------------------------------------------------------------- K3
// h1 = relu(agg1/deg + x @ W1 + b1). 16 rows per block, W1 (32KB) in LDS.
__global__ __launch_bounds__(256) void k3_layer1(
    const float* __restrict__ x, const float* __restrict__ W1,
    const float* __restrict__ b1, const float* __restrict__ agg1,
    const float* __restrict__ deg, float* __restrict__ h1) {
    __shared__ float W1s[NODE_DIM * HIDDEN];   // 32 KB
    __shared__ float xs[16 * NODE_DIM];        // 4 KB
    int tid  = threadIdx.x;
    int base = blockIdx.x * 16;
    for (int i = tid; i < NODE_DIM * HIDDEN; i += 256) W1s[i] = W1[i];
    for (int i = tid; i < 16 * NODE_DIM; i += 256)     xs[i]  = x[base * NODE_DIM + i];
    __syncthreads();
    int r2 = tid >> 7;          // 0..1
    int c  = tid & 127;         // channel
    float bias = b1[c];
    for (int rr = 0; rr < 8; ++rr) {
        int row  = rr * 2 + r2;
        int grow = base + row;
        float acc = 0.f;
        #pragma unroll
        for (int k = 0; k < NODE_DIM; ++k)
            acc = fmaf(xs[row * NODE_DIM + k], W1s[k * HIDDEN + c], acc);
        float d = deg[grow];
        float a = agg1[grow] / (d > 0.f ? d : 1.f);
        float v = a + acc + bias;
        h1[grow * HIDDEN + c] = v > 0.f ? v : 0.f;
    }
}

// ---------------------------------------------------------------- K4
// s2[i] = rowsum(h1[i,0:128]); zero agg2. One wave per row.
__global__ __launch_bounds__(256) void k4_rowsum128(
    const float* __restrict__ h1, float* __restrict__ s2,
    float* __restrict__ agg2) {
    int row  = blockIdx.x * 4 + (threadIdx.x >> 6);
    int lane = threadIdx.x & 63;
    const float* p = h1 + row * HIDDEN;
    float v = p[lane] + p[lane + 64];
    for (int off = 32; off; off >>= 1) v += __shfl_xor(v, off);
    if (lane == 0) { s2[row] = v; agg2[row] = 0.f; }
}

// ---------------------------------------------------------------- K6
// left/right = (relu(agg2/deg + h1 @ W2 + b2)) . w_lin halves.
// h2 never materialized. W2 staged in two 32KB K-chunks. 16 rows/block, 4/wave.
__global__ __launch_bounds__(256) void k6_layer2(
    const float* __restrict__ h1, const float* __restrict__ W2,
    const float* __restrict__ b2, const float* __restrict__ agg2,
    const float* __restrict__ deg, const float* __restrict__ wlin,
    float* __restrict__ left, float* __restrict__ right) {
    __shared__ float W2s[64 * HIDDEN];   // 32 KB (one K-chunk)
    __shared__ float hs[16 * HIDDEN];    // 8 KB
    int tid  = threadIdx.x;
    int base = blockIdx.x * 16;
    for (int i = tid; i < 16 * HIDDEN; i += 256) hs[i] = h1[base * HIDDEN + i];

    int wave = tid >> 6, lane = tid & 63;
    float acc[4][2];
    #pragma unroll
    for (int wr = 0; wr < 4; ++wr) { acc[wr][0] = 0.f; acc[wr][1] = 0.f; }

    for (int chunk = 0; chunk < 2; ++chunk) {
        __syncthreads();
        for (int i = tid; i < 64 * HIDDEN; i += 256)
            W2s[i] = W2[chunk * 64 * HIDDEN + i];
        __syncthreads();
        #pragma unroll
        for (int wr = 0; wr < 4; ++wr) {
            int row = wave * 4 + wr;
            #pragma unroll
            for (int half = 0; half < 2; ++half) {
                int c = half * 64 + lane;
                float a = acc[wr][half];
                #pragma unroll
                for (int k = 0; k < 64; ++k)
                    a = fmaf(hs[row * HIDDEN + chunk * 64 + k], W2s[k * HIDDEN + c], a);
                acc[wr][half] = a;
            }
        }
    }

    #pragma unroll
    for (int wr = 0; wr < 4; ++wr) {
        int row  = wave * 4 + wr;
        int grow = base + row;
        float d  = deg[grow];
        float ag = agg2[grow] / (d > 0.f ? d : 1.f);
        float lp = 0.f, rp = 0.f;
        #pragma unroll
        for (int half = 0; half < 2; ++half) {
            int c = half * 64 + lane;
            float hv = ag + acc[wr][half] + b2[c];
            hv = hv > 0.f ? hv : 0.f;
            lp = fmaf(hv, wlin[c], lp);
            rp = fmaf(hv, wlin[HIDDEN + c], rp);
        }
        for (int off = 32; off; off >>= 1) {
            lp += __shfl_xor(lp, off);
            rp += __shfl_xor(rp, off);
        }
        if (lane == 0) { left[grow] = lp; right[grow] = rp; }
    }
}

// ---------------------------------------------------------------- K7
// out[r*2048 + j] = sigmoid(left[r] + right[(r/2048)*2048 + j] + b_lin)
// float4 stores; 134 MB write is the roofline.
__global__ __launch_bounds__(256) void k7_scores(
    const float* __restrict__ left, const float* __restrict__ right,
    const float* __restrict__ blin, float* __restrict__ out) {
    int t  = blockIdx.x * blockDim.x + threadIdx.x;   // 8,388,608 threads
    int r  = t >> 9;                                  // global row 0..16383
    int j4 = (t & 511) << 2;                          // j base (step 4)
    int b  = r >> 11;                                 // graph id
    float L = left[r] + blin[0];
    float4 rv = *reinterpret_cast<const float4*>(&right[(b << 11) + j4]);
    float4 o;
    o.x = 1.f / (1.f + __expf(-(L + rv.x)));
    o.y = 1.f / (1.f + __expf(-(L + rv.y)));
    o.z = 1.f / (1.f + __expf(-(L + rv.z)));
    o.w = 1.f / (1.f + __expf(-(L + rv.w)));
    *reinterpret_cast<float4*>(&out[(r << 11) + j4]) = o;
}

// ---------------------------------------------------------------- launch
extern "C" void kernel_launch(void* const* d_in, const int* in_sizes, int n_in,
                              void* d_out, int out_size, void* d_ws, size_t ws_size,
                              hipStream_t stream) {
    const float* x    = (const float*)d_in[0];
    const void*  ei   = d_in[1];
    const float* W1   = (const float*)d_in[2];
    const float* b1   = (const float*)d_in[3];
    const float* W2   = (const float*)d_in[4];
    const float* b2   = (const float*)d_in[5];
    const float* wlin = (const float*)d_in[6];
    const float* blin = (const float*)d_in[7];
    int E = in_sizes[1] / 2;

    float* ws    = (float*)d_ws;
    float* s1    = ws;                    // N
    float* agg1  = ws + 1 * N_TOTAL;
    float* deg   = ws + 2 * N_TOTAL;
    float* s2    = ws + 3 * N_TOTAL;
    float* agg2  = ws + 4 * N_TOTAL;
    float* left  = ws + 5 * N_TOTAL;
    float* right = ws + 6 * N_TOTAL;
    float* h1    = ws + 7 * N_TOTAL;      // N * 128
    int*   flag  = (int*)(ws + 7 * N_TOTAL + N_TOTAL * HIDDEN);
    float* out   = (float*)d_out;

    k_detect_idx<<<1, 64, 0, stream>>>((const int*)ei, flag);
    k1_rowsum64<<<N_TOTAL / 4, 256, 0, stream>>>(x, s1, agg1, deg);
    k_edge<<<(E + 255) / 256, 256, 0, stream>>>(ei, E, flag, s1, agg1, deg);
    k3_layer1<<<N_TOTAL / 16, 256, 0, stream>>>(x, W1, b1, agg1, deg, h1);
    k4_rowsum128<<<N_TOTAL / 4, 256, 0, stream>>>(h1, s2, agg2);
    k_edge<<<(E + 255) / 256, 256, 0, stream>>>(ei, E, flag, s2, agg2, nullptr);
    k6_layer2<<<N_TOTAL / 16, 256, 0, stream>>>(h1, W2, b2, agg2, deg, wlin, left, right);
    k7_scores<<<(N_TOTAL * (NPG / 4)) / 256, 256, 0, stream>>>(left, right, blin, out);
}

// Round 2
// 149.024 us; speedup vs baseline: 1.1611x; 1.1611x over previous
//
#include <hip/hip_runtime.h>

#define N_TOTAL 16384
#define NODE_DIM 64
#define HIDDEN 128
#define NPG 2048
#define NGRAPH 8

// ---------------------------------------------------------------- K1
// s[i] = rowsum(x[i,0:64]); zero agg1/deg; block 0 also detects idx width.
__global__ __launch_bounds__(256) void k1_rowsum64(
    const float* __restrict__ x, float* __restrict__ s,
    float* __restrict__ agg1, float* __restrict__ deg,
    const int* __restrict__ ei_words, int* __restrict__ flag) {
    if (blockIdx.x == 0 && threadIdx.x == 0) {
        // int64 little-endian with values < 2^31 => every odd word is 0.
        int odd_nonzero = 0;
        for (int i = 0; i < 256; ++i)
            if (ei_words[2 * i + 1] != 0) odd_nonzero = 1;
        *flag = odd_nonzero;   // 1 => int32 layout, 0 => int64 layout
    }
    int row  = blockIdx.x * 4 + (threadIdx.x >> 6);
    int lane = threadIdx.x & 63;
    float v = x[row * NODE_DIM + lane];
    for (int off = 32; off; off >>= 1) v += __shfl_xor(v, off);
    if (lane == 0) { s[row] = v; agg1[row] = 0.f; deg[row] = 0.f; }
}

// ---------------------------------------------------------------- K2/K5
// Edge scatter: agg[dst] += s[src]; optionally deg[dst] += 1.
__global__ __launch_bounds__(256) void k_edge(
    const void* __restrict__ ei_raw, int E, const int* __restrict__ flag,
    const float* __restrict__ s, float* __restrict__ agg,
    float* __restrict__ deg /* may be nullptr */) {
    int e = blockIdx.x * blockDim.x + threadIdx.x;
    if (e >= E) return;
    int sidx, didx;
    if (*flag) {
        const int* ei = (const int*)ei_raw;
        sidx = ei[e]; didx = ei[E + e];
    } else {
        const long long* ei = (const long long*)ei_raw;
        sidx = (int)ei[e]; didx = (int)ei[E + e];
    }
    atomicAdd(&agg[didx], s[sidx]);
    if (deg) atomicAdd(&deg[didx], 1.0f);
}

// ---------------------------------------------------------------- K3
// h1 = relu(agg1/deg + x @ W1 + b1), fused rowsum(h1) -> s2, agg2 = 0.
// 16 rows/block. Thread t: channels c4..c4+3 (c4=(t&31)*4), rows rg*2, rg*2+1.
// Inner loop: 1 ds_read_b128 (W) + 2 broadcasts (x) per 8 fma.
__global__ __launch_bounds__(256) void k3_layer1(
    const float* __restrict__ x, const float* __restrict__ W1,
    const float* __restrict__ b1, const float* __restrict__ agg1,
    const float* __restrict__ deg, float* __restrict__ h1,
    float* __restrict__ s2, float* __restrict__ agg2) {
    __shared__ float W1s[NODE_DIM * HIDDEN];   // 32 KB
    __shared__ float xs[16 * NODE_DIM];        // 4 KB
    int tid  = threadIdx.x;
    int base = blockIdx.x * 16;
    {   // cooperative float4 loads
        const float4* Wv = (const float4*)W1;
        float4* Wsv = (float4*)W1s;
        for (int i = tid; i < NODE_DIM * HIDDEN / 4; i += 256) Wsv[i] = Wv[i];
        const float4* xv = (const float4*)(x + base * NODE_DIM);
        float4* xsv = (float4*)xs;
        for (int i = tid; i < 16 * NODE_DIM / 4; i += 256) xsv[i] = xv[i];
    }
    __syncthreads();
    int lane32 = tid & 31;
    int rg     = tid >> 5;            // 0..7
    int c4     = lane32 * 4;
    int row0   = rg * 2, row1 = rg * 2 + 1;
    float a00 = 0.f, a01 = 0.f, a02 = 0.f, a03 = 0.f;
    float a10 = 0.f, a11 = 0.f, a12 = 0.f, a13 = 0.f;
    #pragma unroll
    for (int k = 0; k < NODE_DIM; ++k) {
        float4 w = *(const float4*)&W1s[k * HIDDEN + c4];
        float x0 = xs[row0 * NODE_DIM + k];
        float x1 = xs[row1 * NODE_DIM + k];
        a00 = fmaf(x0, w.x, a00); a01 = fmaf(x0, w.y, a01);
        a02 = fmaf(x0, w.z, a02); a03 = fmaf(x0, w.w, a03);
        a10 = fmaf(x1, w.x, a10); a11 = fmaf(x1, w.y, a11);
        a12 = fmaf(x1, w.z, a12); a13 = fmaf(x1, w.w, a13);
    }
    float4 bb = *(const float4*)&b1[c4];
    // row0 epilogue
    {
        int grow = base + row0;
        float d = deg[grow];
        float a = agg1[grow] / (d > 0.f ? d : 1.f);
        float4 v;
        v.x = fmaxf(a + a00 + bb.x, 0.f);
        v.y = fmaxf(a + a01 + bb.y, 0.f);
        v.z = fmaxf(a + a02 + bb.z, 0.f);
        v.w = fmaxf(a + a03 + bb.w, 0.f);
        *(float4*)&h1[grow * HIDDEN + c4] = v;
        float rs = v.x + v.y + v.z + v.w;
        for (int off = 16; off; off >>= 1) rs += __shfl_xor(rs, off);
        if (lane32 == 0) { s2[grow] = rs; agg2[grow] = 0.f; }
    }
    // row1 epilogue
    {
        int grow = base + row1;
        float d = deg[grow];
        float a = agg1[grow] / (d > 0.f ? d : 1.f);
        float4 v;
        v.x = fmaxf(a + a10 + bb.x, 0.f);
        v.y = fmaxf(a + a11 + bb.y, 0.f);
        v.z = fmaxf(a + a12 + bb.z, 0.f);
        v.w = fmaxf(a + a13 + bb.w, 0.f);
        *(float4*)&h1[grow * HIDDEN + c4] = v;
        float rs = v.x + v.y + v.z + v.w;
        for (int off = 16; off; off >>= 1) rs += __shfl_xor(rs, off);
        if (lane32 == 0) { s2[grow] = rs; agg2[grow] = 0.f; }
    }
}

// ---------------------------------------------------------------- K6
// left/right = relu(agg2/deg + h1 @ W2 + b2) . w_lin halves; h2 never stored.
// Same thread mapping as K3; W2 staged in two 32 KB K-chunks.
__global__ __launch_bounds__(256) void k6_layer2(
    const float* __restrict__ h1, const float* __restrict__ W2,
    const float* __restrict__ b2, const float* __restrict__ agg2,
    const float* __restrict__ deg, const float* __restrict__ wlin,
    float* __restrict__ left, float* __restrict__ right) {
    __shared__ float W2s[64 * HIDDEN];   // 32 KB (one K-chunk)
    __shared__ float hs[16 * HIDDEN];    // 8 KB
    int tid  = threadIdx.x;
    int base = blockIdx.x * 16;
    {
        const float4* hv = (const float4*)(h1 + base * HIDDEN);
        float4* hsv = (float4*)hs;
        for (int i = tid; i < 16 * HIDDEN / 4; i += 256) hsv[i] = hv[i];
    }
    int lane32 = tid & 31;
    int rg     = tid >> 5;
    int c4     = lane32 * 4;
    int row0   = rg * 2, row1 = rg * 2 + 1;
    float a00 = 0.f, a01 = 0.f, a02 = 0.f, a03 = 0.f;
    float a10 = 0.f, a11 = 0.f, a12 = 0.f, a13 = 0.f;
    for (int chunk = 0; chunk < 2; ++chunk) {
        __syncthreads();
        {
            const float4* Wv = (const float4*)(W2 + chunk * 64 * HIDDEN);
            float4* Wsv = (float4*)W2s;
            for (int i = tid; i < 64 * HIDDEN / 4; i += 256) Wsv[i] = Wv[i];
        }
        __syncthreads();
        int kb = chunk * 64;
        #pragma unroll 8
        for (int k = 0; k < 64; ++k) {
            float4 w = *(const float4*)&W2s[k * HIDDEN + c4];
            float h0 = hs[row0 * HIDDEN + kb + k];
            float h1v = hs[row1 * HIDDEN + kb + k];
            a00 = fmaf(h0, w.x, a00);  a01 = fmaf(h0, w.y, a01);
            a02 = fmaf(h0, w.z, a02);  a03 = fmaf(h0, w.w, a03);
            a10 = fmaf(h1v, w.x, a10); a11 = fmaf(h1v, w.y, a11);
            a12 = fmaf(h1v, w.z, a12); a13 = fmaf(h1v, w.w, a13);
        }
    }
    float4 bb  = *(const float4*)&b2[c4];
    float4 wl  = *(const float4*)&wlin[c4];
    float4 wr  = *(const float4*)&wlin[HIDDEN + c4];
    // row0
    {
        int grow = base + row0;
        float d  = deg[grow];
        float ag = agg2[grow] / (d > 0.f ? d : 1.f);
        float h0 = fmaxf(ag + a00 + bb.x, 0.f);
        float h1e = fmaxf(ag + a01 + bb.y, 0.f);
        float h2e = fmaxf(ag + a02 + bb.z, 0.f);
        float h3e = fmaxf(ag + a03 + bb.w, 0.f);
        float lp = h0 * wl.x + h1e * wl.y + h2e * wl.z + h3e * wl.w;
        float rp = h0 * wr.x + h1e * wr.y + h2e * wr.z + h3e * wr.w;
        for (int off = 16; off; off >>= 1) {
            lp += __shfl_xor(lp, off);
            rp += __shfl_xor(rp, off);
        }
        if (lane32 == 0) { left[grow] = lp; right[grow] = rp; }
    }
    // row1
    {
        int grow = base + row1;
        float d  = deg[grow];
        float ag = agg2[grow] / (d > 0.f ? d : 1.f);
        float h0 = fmaxf(ag + a10 + bb.x, 0.f);
        float h1e = fmaxf(ag + a11 + bb.y, 0.f);
        float h2e = fmaxf(ag + a12 + bb.z, 0.f);
        float h3e = fmaxf(ag + a13 + bb.w, 0.f);
        float lp = h0 * wl.x + h1e * wl.y + h2e * wl.z + h3e * wl.w;
        float rp = h0 * wr.x + h1e * wr.y + h2e * wr.z + h3e * wr.w;
        for (int off = 16; off; off >>= 1) {
            lp += __shfl_xor(lp, off);
            rp += __shfl_xor(rp, off);
        }
        if (lane32 == 0) { left[grow] = lp; right[grow] = rp; }
    }
}

// ---------------------------------------------------------------- K7
// out[r*2048 + j] = sigmoid(left[r] + right[(r>>11)*2048 + j] + b_lin)
__global__ __launch_bounds__(256) void k7_scores(
    const float* __restrict__ left, const float* __restrict__ right,
    const float* __restrict__ blin, float* __restrict__ out) {
    int t  = blockIdx.x * blockDim.x + threadIdx.x;
    int r  = t >> 9;
    int j4 = (t & 511) << 2;
    int b  = r >> 11;
    float L = left[r] + blin[0];
    float4 rv = *reinterpret_cast<const float4*>(&right[(b << 11) + j4]);
    float4 o;
    o.x = 1.f / (1.f + __expf(-(L + rv.x)));
    o.y = 1.f / (1.f + __expf(-(L + rv.y)));
    o.z = 1.f / (1.f + __expf(-(L + rv.z)));
    o.w = 1.f / (1.f + __expf(-(L + rv.w)));
    *reinterpret_cast<float4*>(&out[(r << 11) + j4]) = o;
}

// ---------------------------------------------------------------- launch
extern "C" void kernel_launch(void* const* d_in, const int* in_sizes, int n_in,
                              void* d_out, int out_size, void* d_ws, size_t ws_size,
                              hipStream_t stream) {
    const float* x    = (const float*)d_in[0];
    const void*  ei   = d_in[1];
    const float* W1   = (const float*)d_in[2];
    const float* b1   = (const float*)d_in[3];
    const float* W2   = (const float*)d_in[4];
    const float* b2   = (const float*)d_in[5];
    const float* wlin = (const float*)d_in[6];
    const float* blin = (const float*)d_in[7];
    int E = in_sizes[1] / 2;

    float* ws    = (float*)d_ws;
    float* s1    = ws;                    // N
    float* agg1  = ws + 1 * N_TOTAL;
    float* deg   = ws + 2 * N_TOTAL;
    float* s2    = ws + 3 * N_TOTAL;
    float* agg2  = ws + 4 * N_TOTAL;
    float* left  = ws + 5 * N_TOTAL;
    float* right = ws + 6 * N_TOTAL;
    float* h1    = ws + 7 * N_TOTAL;      // N * 128
    int*   flag  = (int*)(ws + 7 * N_TOTAL + N_TOTAL * HIDDEN);
    float* out   = (float*)d_out;

    k1_rowsum64<<<N_TOTAL / 4, 256, 0, stream>>>(x, s1, agg1, deg,
                                                 (const int*)ei, flag);
    k_edge<<<(E + 255) / 256, 256, 0, stream>>>(ei, E, flag, s1, agg1, deg);
    k3_layer1<<<N_TOTAL / 16, 256, 0, stream>>>(x, W1, b1, agg1, deg, h1, s2, agg2);
    k_edge<<<(E + 255) / 256, 256, 0, stream>>>(ei, E, flag, s2, agg2, nullptr);
    k6_layer2<<<N_TOTAL / 16, 256, 0, stream>>>(h1, W2, b2, agg2, deg, wlin, left, right);
    k7_scores<<<(N_TOTAL * (NPG / 4)) / 256, 256, 0, stream>>>(left, right, blin, out);
}